// Round 4
// baseline (33.708 us; speedup 1.0000x reference)
//
#include <hip/hip_runtime.h>

// CRF-RNN 1-D message passing — fully register-resident, zero-LDS version.
// B=16, N=100000, K=11 (HALF=5), 5 Jacobi iterations.
// One wave per block; thread owns G=8 consecutive positions. Features loaded as
// aligned dwordx4 (compile-time unpack); q-halo exchanged via __shfl (no LDS,
// no barriers). Edge chunks (first/last per image) take a scalar clamped path.

constexpr int BLK   = 64;            // one wave
constexpr int G     = 8;             // positions per thread
constexpr int E     = BLK * G;       // 512 ext positions per block
constexpr int HL    = 28;            // halo each side (>=25, mult of 4 for alignment)
constexpr int C     = E - 2 * HL;    // 456 outputs per block (mult of 4)
constexpr int NITER = 5;
constexpr float EPS = 1e-8f;

__device__ __forceinline__ float frcp(float x) { return __builtin_amdgcn_rcpf(x); }
__device__ __forceinline__ float sigm(float x) { return frcp(1.0f + __expf(-x)); }

__global__ __launch_bounds__(BLK, 3) void crf_kernel(
    const float* __restrict__ logits, const float* __restrict__ p,
    float* __restrict__ out, int N, int chunks_per_b)
{
  const int b     = blockIdx.x / chunks_per_b;
  const int chunk = blockIdx.x % chunks_per_b;
  const int s0    = chunk * C - HL;       // global index of ext position 0 (≡0 mod 4)
  const int t     = threadIdx.x;
  const int gb    = s0 + G * t;           // global index of own pos 0 (≡0 mod 4)
  const float* lg = logits + (size_t)b * N;
  const float* pp = p + (size_t)b * N * 3;

  // interior: all window/logit indices in [0, N) -> no clamps, no masks
  const bool interior = (s0 >= 5) && (s0 + E + 5 < N);

  // ---- features for window positions [gb-5, gb+13) ----
  float f[18][3];
  if (interior) {
    // byte range [12*(gb-5)-4, +224) is 16B-aligned (12*gb ≡ 0 mod 16)
    const float4* vp = (const float4*)(pp + 3 * gb - 16);
    float va[56];
    #pragma unroll
    for (int m = 0; m < 14; ++m) {
      float4 v = vp[m];
      va[4 * m + 0] = v.x; va[4 * m + 1] = v.y;
      va[4 * m + 2] = v.z; va[4 * m + 3] = v.w;
    }
    #pragma unroll
    for (int j = 0; j < 18; ++j)
      #pragma unroll
      for (int c = 0; c < 3; ++c)
        f[j][c] = va[3 * j + c + 1];     // compile-time index: register rename
  } else {
    #pragma unroll
    for (int j = 0; j < 18; ++j) {
      int g  = gb + j - 5;
      int gc = min(max(g, 0), N - 1);
      const float* src = pp + 3 * (size_t)gc;
      f[j][0] = src[0]; f[j][1] = src[1]; f[j][2] = src[2];
    }
  }

  // ---- unary ----
  float un[G];
  if (interior) {
    const float4* up = (const float4*)(lg + gb);
    float4 u0 = up[0], u1 = up[1];
    un[0] = u0.x; un[1] = u0.y; un[2] = u0.z; un[3] = u0.w;
    un[4] = u1.x; un[5] = u1.y; un[6] = u1.z; un[7] = u1.w;
  } else {
    #pragma unroll
    for (int k = 0; k < G; ++k) {
      int gc = min(max(gb + k, 0), N - 1);
      un[k] = lg[gc];
    }
  }

  // ---- pairwise weights (each unique weight computed once) ----
  // wr[k][d] = w(pos k -> k+d+1), wl[k][d] = w(pos k-d-1 -> k); pos rel. to gb
  float wr[G][5], wl[G][5];
  #pragma unroll
  for (int i = 0; i < 13; ++i) {        // window center index: pos = gb-5+i
    #pragma unroll
    for (int d = 0; d < 5; ++d) {
      float d0 = f[i][0] - f[i + d + 1][0];
      float d1 = f[i][1] - f[i + d + 1][1];
      float d2 = f[i][2] - f[i + d + 1][2];
      float ex = __expf(-0.5f * (d0 * d0 + d1 * d1 + d2 * d2));
      if (!interior) {
        int g = gb + i - 5;
        ex = (g >= 0 && g + d + 1 < N) ? ex : 0.0f;
      }
      if (i >= 5) wr[i - 5][d] = ex;
      const int kl = i + d - 4;          // compile-time after unroll
      if (kl >= 0 && kl < G) wl[kl][d] = ex;
    }
  }
  // normalize
  #pragma unroll
  for (int k = 0; k < G; ++k) {
    float ws = EPS;
    #pragma unroll
    for (int d = 0; d < 5; ++d) ws += wr[k][d] + wl[k][d];
    float inv = frcp(ws);
    #pragma unroll
    for (int d = 0; d < 5; ++d) { wr[k][d] *= inv; wl[k][d] *= inv; }
  }

  // ---- q0 ----
  float q[G];
  #pragma unroll
  for (int k = 0; k < G; ++k) q[k] = sigm(un[k]);

  // ---- 5 Jacobi iterations; halo via wave shuffles (no LDS, no barriers) ----
  #pragma unroll
  for (int it = 0; it < NITER; ++it) {
    float qx[18];                        // q at ext position (gb-5+j)
    #pragma unroll
    for (int j = 0; j < 5; ++j) qx[j] = __shfl_up(q[3 + j], 1);       // lane t-1's q[3..7]
    #pragma unroll
    for (int k = 0; k < G; ++k) qx[5 + k] = q[k];
    #pragma unroll
    for (int j = 0; j < 5; ++j) qx[13 + j] = __shfl_down(q[j], 1);    // lane t+1's q[0..4]
    // lanes 0/63 get garbage halo -> eroded inside HL=28 after 5 iters

    #pragma unroll
    for (int k = 0; k < G; ++k) {
      float msg = 0.0f;
      #pragma unroll
      for (int d = 0; d < 5; ++d) {
        msg += wl[k][d] * qx[5 + k - d - 1];
        msg += wr[k][d] * qx[5 + k + d + 1];
      }
      q[k] = sigm(un[k] + msg);
    }
  }

  // ---- aligned float4 stores of owned outputs ----
  float* ob = out + (size_t)b * N;
  #pragma unroll
  for (int h = 0; h < 2; ++h) {
    const int e0 = G * t + 4 * h;
    if (e0 >= HL && e0 < E - HL) {
      const int gx = chunk * C + (e0 - HL);
      float4 v = make_float4(q[4 * h], q[4 * h + 1], q[4 * h + 2], q[4 * h + 3]);
      if (interior || gx + 3 < N) {
        *(float4*)(ob + gx) = v;
      } else {
        #pragma unroll
        for (int j = 0; j < 4; ++j)
          if (gx + j < N) ob[gx + j] = (&v.x)[j];
      }
    }
  }
}

extern "C" void kernel_launch(void* const* d_in, const int* in_sizes, int n_in,
                              void* d_out, int out_size, void* d_ws, size_t ws_size,
                              hipStream_t stream) {
  const float* logits = (const float*)d_in[0];
  const float* p      = (const float*)d_in[1];
  float* out          = (float*)d_out;
  const int N = 100000;
  const int B = in_sizes[0] / N;                 // 16
  const int chunks_per_b = (N + C - 1) / C;      // 220
  dim3 grid(B * chunks_per_b), block(BLK);
  crf_kernel<<<grid, block, 0, stream>>>(logits, p, out, N, chunks_per_b);
}

// Round 5
// 19.011 us; speedup vs baseline: 1.7731x; 1.7731x over previous
//
#include <hip/hip_runtime.h>

// CRF-RNN 1-D message passing. B=16, N=100000, K=11 (HALF=5), 5 iterations.
// One wave per block; thread owns G=4 consecutive positions.
// Own-only aligned float4 loads; feature halo via 30 one-time shuffles;
// weights normalized in registers; per-iteration q-halo via tiny LDS float4
// exchange (canonical conflict-free pattern). Edge blocks take scalar path.

constexpr int BLK   = 64;            // one wave
constexpr int G     = 4;             // positions per thread
constexpr int E     = BLK * G;       // 256 ext positions per block
constexpr int HL    = 28;            // halo each side (>=25, mult of 4)
constexpr int C     = E - 2 * HL;    // 200 outputs per block
constexpr int NITER = 5;
constexpr float EPS = 1e-8f;

__device__ __forceinline__ float frcp(float x) { return __builtin_amdgcn_rcpf(x); }
__device__ __forceinline__ float sigm(float x) { return frcp(1.0f + __expf(-x)); }

__global__ __launch_bounds__(BLK, 4) void crf_kernel(
    const float* __restrict__ logits, const float* __restrict__ p,
    float* __restrict__ out, int N, int chunks_per_b)
{
  __shared__ float4 s_q4[BLK];

  const int b     = blockIdx.x / chunks_per_b;
  const int chunk = blockIdx.x % chunks_per_b;
  const int s0    = chunk * C - HL;      // global index of ext position 0 (mod 4 == 0)
  const int t     = threadIdx.x;
  const int gb    = s0 + G * t;          // global index of own pos 0 (mod 4 == 0)
  const float* lg = logits + (size_t)b * N;
  const float* pp = p + (size_t)b * N * 3;

  // interior: every window/logit index in [0, N) -> no clamps, no masks
  const bool interior = (s0 >= 5) && (s0 + E + 5 < N);

  // ---- features for window positions [gb-5, gb+9) ----
  float fx[14][3];                       // fx[j] = features at position gb-5+j
  if (interior) {
    // own positions gb..gb+3 = floats [3gb, 3gb+12), 16B-aligned (gb % 4 == 0)
    float own[12];
    const float4* vp = (const float4*)(pp + 3 * gb);
    float4 v0 = vp[0], v1 = vp[1], v2 = vp[2];
    own[0] = v0.x; own[1]  = v0.y; own[2]  = v0.z; own[3]  = v0.w;
    own[4] = v1.x; own[5]  = v1.y; own[6]  = v1.z; own[7]  = v1.w;
    own[8] = v2.x; own[9]  = v2.y; own[10] = v2.z; own[11] = v2.w;
    // halo features from neighbor lanes (one-time, off the iteration path)
    #pragma unroll
    for (int c = 0; c < 3; ++c) fx[0][c] = __shfl_up(own[9 + c], 2);   // pos gb-5
    #pragma unroll
    for (int j = 0; j < 4; ++j)
      #pragma unroll
      for (int c = 0; c < 3; ++c) fx[1 + j][c] = __shfl_up(own[3 * j + c], 1);
    #pragma unroll
    for (int j = 0; j < 4; ++j)
      #pragma unroll
      for (int c = 0; c < 3; ++c) fx[5 + j][c] = own[3 * j + c];
    #pragma unroll
    for (int j = 0; j < 4; ++j)
      #pragma unroll
      for (int c = 0; c < 3; ++c) fx[9 + j][c] = __shfl_down(own[3 * j + c], 1);
    #pragma unroll
    for (int c = 0; c < 3; ++c) fx[13][c] = __shfl_down(own[c], 2);    // pos gb+8
  } else {
    #pragma unroll
    for (int j = 0; j < 14; ++j) {
      int g  = gb + j - 5;
      int gc = min(max(g, 0), N - 1);
      const float* src = pp + 3 * (size_t)gc;
      fx[j][0] = src[0]; fx[j][1] = src[1]; fx[j][2] = src[2];
    }
  }

  // ---- pairwise weights (each unique weight computed once; dead ones DCE'd) ----
  float wr[G][5], wl[G][5];
  #pragma unroll
  for (int i = 0; i < 9; ++i) {          // left endpoint: position gb-5+i
    #pragma unroll
    for (int d = 0; d < 5; ++d) {
      float d0 = fx[i][0] - fx[i + d + 1][0];
      float d1 = fx[i][1] - fx[i + d + 1][1];
      float d2 = fx[i][2] - fx[i + d + 1][2];
      float ex = __expf(-0.5f * (d0 * d0 + d1 * d1 + d2 * d2));
      if (!interior) {
        int g = gb + i - 5;
        ex = (g >= 0 && g + d + 1 < N) ? ex : 0.0f;
      }
      if (i >= 5) wr[i - 5][d] = ex;     // right-weight of own pos i-5
      const int kl = i + d - 4;          // left-weight of own pos kl
      if (kl >= 0 && kl < G) wl[kl][d] = ex;
    }
  }

  // ---- unary, normalize, q0 ----
  float un[G], q[G];
  if (interior) {
    float4 u = *(const float4*)(lg + gb);
    un[0] = u.x; un[1] = u.y; un[2] = u.z; un[3] = u.w;
  } else {
    #pragma unroll
    for (int k = 0; k < G; ++k) un[k] = lg[min(max(gb + k, 0), N - 1)];
  }
  #pragma unroll
  for (int k = 0; k < G; ++k) {
    float ws = EPS;
    #pragma unroll
    for (int d = 0; d < 5; ++d) ws += wr[k][d] + wl[k][d];
    float inv = frcp(ws);
    #pragma unroll
    for (int d = 0; d < 5; ++d) { wr[k][d] *= inv; wl[k][d] *= inv; }
    q[k] = sigm(un[k]);
  }

  // ---- q-halo exchange addresses (clamped at wave edges; erosion-safe) ----
  const int tL1 = max(t - 1, 0), tL2 = max(t - 2, 0);
  const int tR1 = min(t + 1, BLK - 1), tR2 = min(t + 2, BLK - 1);

  s_q4[t] = make_float4(q[0], q[1], q[2], q[3]);
  __syncthreads();

  // ---- 5 Jacobi iterations ----
  #pragma unroll
  for (int it = 0; it < NITER; ++it) {
    float4 L2 = s_q4[tL2];
    float4 L1 = s_q4[tL1];
    float4 R1 = s_q4[tR1];
    float4 R2 = s_q4[tR2];
    float qx[14];                        // q at position gb-5+j
    qx[0] = L2.w;
    qx[1] = L1.x; qx[2]  = L1.y; qx[3]  = L1.z; qx[4]  = L1.w;
    qx[5] = q[0]; qx[6]  = q[1]; qx[7]  = q[2]; qx[8]  = q[3];
    qx[9] = R1.x; qx[10] = R1.y; qx[11] = R1.z; qx[12] = R1.w;
    qx[13] = R2.x;

    #pragma unroll
    for (int k = 0; k < G; ++k) {
      float msg = 0.0f;
      #pragma unroll
      for (int d = 0; d < 5; ++d) {
        msg += wl[k][d] * qx[5 + k - d - 1];
        msg += wr[k][d] * qx[5 + k + d + 1];
      }
      q[k] = sigm(un[k] + msg);
    }

    if (it != NITER - 1) {
      __syncthreads();
      s_q4[t] = make_float4(q[0], q[1], q[2], q[3]);
      __syncthreads();
    }
  }

  // ---- aligned float4 store of owned outputs ----
  const int e0 = G * t;
  if (e0 >= HL && e0 + G <= E - HL) {
    const int gx = chunk * C + (e0 - HL);
    float* ob = out + (size_t)b * N + gx;
    float4 v = make_float4(q[0], q[1], q[2], q[3]);
    if (gx + 3 < N) {
      *(float4*)ob = v;
    } else {
      #pragma unroll
      for (int j = 0; j < 4; ++j)
        if (gx + j < N) ob[j] = (&v.x)[j];
    }
  }
}

extern "C" void kernel_launch(void* const* d_in, const int* in_sizes, int n_in,
                              void* d_out, int out_size, void* d_ws, size_t ws_size,
                              hipStream_t stream) {
  const float* logits = (const float*)d_in[0];
  const float* p      = (const float*)d_in[1];
  float* out          = (float*)d_out;
  const int N = 100000;
  const int B = in_sizes[0] / N;                 // 16
  const int chunks_per_b = (N + C - 1) / C;      // 500
  dim3 grid(B * chunks_per_b), block(BLK);
  crf_kernel<<<grid, block, 0, stream>>>(logits, p, out, N, chunks_per_b);
}

// Round 6
// 16.915 us; speedup vs baseline: 1.9928x; 1.1239x over previous
//
#include <hip/hip_runtime.h>

// CRF-RNN 1-D message passing. B=16, N=100000, K=11 (HALF=5), 5 iterations.
// One wave per block; thread owns G=4 consecutive positions. Zero LDS, zero
// barriers: feature halo, weight symmetry sharing, and per-iteration q-halo all
// via wave shuffles. Each unique Gaussian weight computed by exactly one lane
// (20 exps/thread); left weights obtained by shfl_up of unnormalized ww.
// Edge blocks (2 per image) take a scalar clamped path with masks.

constexpr int BLK   = 64;            // one wave
constexpr int G     = 4;             // positions per thread
constexpr int E     = BLK * G;       // 256 ext positions per block
constexpr int HL    = 28;            // halo each side (erosion-safe: 8 + 4*5 = 28)
constexpr int C     = E - 2 * HL;    // 200 outputs per block (N = 500*200 exact)
constexpr int NITER = 5;
constexpr float EPS = 1e-8f;

__device__ __forceinline__ float frcp(float x) { return __builtin_amdgcn_rcpf(x); }
__device__ __forceinline__ float sigm(float x) { return frcp(1.0f + __expf(-x)); }

__global__ __launch_bounds__(BLK, 4) void crf_kernel(
    const float* __restrict__ logits, const float* __restrict__ p,
    float* __restrict__ out, int N, int chunks_per_b)
{
  const int b     = blockIdx.x / chunks_per_b;
  const int chunk = blockIdx.x - b * chunks_per_b;
  const int s0    = chunk * C - HL;      // global index of ext position 0 (mod 4 == 0)
  const int t     = threadIdx.x;
  const int gb    = s0 + G * t;          // global index of own pos 0 (mod 4 == 0)
  const float* lg = logits + (size_t)b * N;
  const float* pp = p + (size_t)b * N * 3;

  // interior: every index this block touches is in [0, N) -> no clamps/masks
  const bool interior = (s0 >= 5) && (s0 + E + 5 < N);

  // ---- own features (positions gb..gb+3) + unary: aligned float4 loads ----
  float own[12], un[G];
  if (interior) {
    const float4* vp = (const float4*)(pp + 3 * gb);   // 16B-aligned (gb%4==0)
    float4 v0 = vp[0], v1 = vp[1], v2 = vp[2];
    own[0] = v0.x; own[1]  = v0.y; own[2]  = v0.z; own[3]  = v0.w;
    own[4] = v1.x; own[5]  = v1.y; own[6]  = v1.z; own[7]  = v1.w;
    own[8] = v2.x; own[9]  = v2.y; own[10] = v2.z; own[11] = v2.w;
    float4 u = *(const float4*)(lg + gb);
    un[0] = u.x; un[1] = u.y; un[2] = u.z; un[3] = u.w;
  } else {
    #pragma unroll
    for (int k = 0; k < G; ++k) {
      int gc = min(max(gb + k, 0), N - 1);
      own[3 * k + 0] = pp[3 * (size_t)gc + 0];
      own[3 * k + 1] = pp[3 * (size_t)gc + 1];
      own[3 * k + 2] = pp[3 * (size_t)gc + 2];
      un[k] = lg[gc];
    }
  }

  // ---- right-halo features: positions gb+4..gb+8 (15 shuffles) ----
  float fh[5][3];
  #pragma unroll
  for (int j = 0; j < 4; ++j)
    #pragma unroll
    for (int c = 0; c < 3; ++c)
      fh[j][c] = __shfl_down(own[3 * j + c], 1);       // lane t+1's pos j
  #pragma unroll
  for (int c = 0; c < 3; ++c)
    fh[4][c] = __shfl_down(own[c], 2);                 // lane t+2's pos 0

  // ---- own-start upper weights: ww[k][d] = w(gb+k, gb+k+d+1), 20 exps ----
  float ww[G][5];
  #pragma unroll
  for (int k = 0; k < G; ++k) {
    #pragma unroll
    for (int d = 0; d < 5; ++d) {
      const int j = k + d + 1;                         // partner local idx 1..8
      float p0 = (j < 4) ? own[3 * j + 0] : fh[j - 4][0];
      float p1 = (j < 4) ? own[3 * j + 1] : fh[j - 4][1];
      float p2 = (j < 4) ? own[3 * j + 2] : fh[j - 4][2];
      float d0 = own[3 * k + 0] - p0;
      float d1 = own[3 * k + 1] - p1;
      float d2 = own[3 * k + 2] - p2;
      float ex = __expf(-0.5f * (d0 * d0 + d1 * d1 + d2 * d2));
      if (!interior)
        ex = (gb + k >= 0 && gb + k + d + 1 < N) ? ex : 0.0f;
      ww[k][d] = ex;
    }
  }

  // ---- left weights by symmetry: wl[k][d] = w(start = gb+k-d-1, ., d) ----
  // start s = k-d-1: s>=0 own ww; s in [-4,-1] from lane t-1; s=-5 from t-2.
  float wl[G][5];
  #pragma unroll
  for (int k = 0; k < G; ++k) {
    #pragma unroll
    for (int d = 0; d < 5; ++d) {
      const int s = k - d - 1;                         // compile-time
      float v;
      if (s >= 0)       v = ww[s][d];
      else if (s >= -4) v = __shfl_up(ww[s + 4][d], 1);
      else              v = __shfl_up(ww[3][d], 2);
      wl[k][d] = v;
    }
  }

  // ---- normalize (per center position) + q0 ----
  float q[G];
  #pragma unroll
  for (int k = 0; k < G; ++k) {
    float ws = EPS;
    #pragma unroll
    for (int d = 0; d < 5; ++d) ws += ww[k][d] + wl[k][d];
    float inv = frcp(ws);
    #pragma unroll
    for (int d = 0; d < 5; ++d) { ww[k][d] *= inv; wl[k][d] *= inv; }
    q[k] = sigm(un[k]);
  }

  // ---- 5 Jacobi iterations; q-halo via 10 shuffles, no LDS/barriers ----
  #pragma unroll
  for (int it = 0; it < NITER; ++it) {
    float qx[14];                        // q at ext position gb-5+j
    qx[0] = __shfl_up(q[3], 2);
    #pragma unroll
    for (int j = 0; j < 4; ++j) qx[1 + j] = __shfl_up(q[j], 1);
    #pragma unroll
    for (int k = 0; k < G; ++k) qx[5 + k] = q[k];
    #pragma unroll
    for (int j = 0; j < 4; ++j) qx[9 + j] = __shfl_down(q[j], 1);
    qx[13] = __shfl_down(q[0], 2);
    // lanes 0,1 / 62,63 get garbage halo; wrongness eroded within HL=28.

    #pragma unroll
    for (int k = 0; k < G; ++k) {
      float msg = 0.0f;
      #pragma unroll
      for (int d = 0; d < 5; ++d) {
        msg += wl[k][d] * qx[5 + k - d - 1];
        msg += ww[k][d] * qx[5 + k + d + 1];
      }
      q[k] = sigm(un[k] + msg);
    }
  }

  // ---- aligned float4 store of owned outputs (ext [HL, E-HL)) ----
  const int e0 = G * t;
  if (e0 >= HL && e0 + G <= E - HL) {
    const int gx = chunk * C + (e0 - HL);
    float* ob = out + (size_t)b * N + gx;
    float4 v = make_float4(q[0], q[1], q[2], q[3]);
    if (gx + 3 < N) {
      *(float4*)ob = v;
    } else {
      #pragma unroll
      for (int j = 0; j < 4; ++j)
        if (gx + j < N) ob[j] = (&v.x)[j];
    }
  }
}

extern "C" void kernel_launch(void* const* d_in, const int* in_sizes, int n_in,
                              void* d_out, int out_size, void* d_ws, size_t ws_size,
                              hipStream_t stream) {
  const float* logits = (const float*)d_in[0];
  const float* p      = (const float*)d_in[1];
  float* out          = (float*)d_out;
  const int N = 100000;
  const int B = in_sizes[0] / N;                 // 16
  const int chunks_per_b = (N + C - 1) / C;      // 500
  dim3 grid(B * chunks_per_b), block(BLK);
  crf_kernel<<<grid, block, 0, stream>>>(logits, p, out, N, chunks_per_b);
}